// Round 5
// baseline (4537.690 us; speedup 1.0000x reference)
//
#include <hip/hip_runtime.h>

#define TTOT 16384   // 4 * 4096 tokens
#define DDIM 2048
#define NEXP 64
#define KS   128     // K slice staged in LDS per stage
#define NSTG (DDIM / KS)   // 16 stages
#define TPB2 16      // tokens per block (4 waves x 4 tokens/wave)
#define STRIDE 132   // LDS row stride in floats: 128 + 4 pad (4-bank shift/row)
#define BUFSZ (TPB2 * STRIDE)

// Lane = 16 expert-groups x 4 tokens: lane owns experts [4g,4g+4) of one
// token. x: LDS double-buffered, read as ds_read_b128 (16 rows x 4-way
// same-address, pad->conflict-free; in-order lgkm -> pipelines). W: per-lane
// float4 VMEM (1 instr/d, TA-merged, L1-hot, vmcnt-pipelined). Staging loads
// for stage s+1 issue before stage s compute -> HBM latency hidden. No
// scalar-path x (R3's lgkmcnt(0) serialization), no per-load VALU addr (R4).
__global__ __launch_bounds__(256, 4)
void moe_router(const float* __restrict__ x, const float* __restrict__ W,
                float* __restrict__ out)
{
    __shared__ float xs[2 * BUFSZ];
    const int tid  = threadIdx.x;
    const int lane = tid & 63;
    const int wq   = __builtin_amdgcn_readfirstlane(tid >> 6);
    const int g    = lane & 15;             // expert group: experts [4g, 4g+4)
    const int trow = wq * 4 + (lane >> 4);  // block-local token 0..15
    const int tokBase = blockIdx.x * TPB2;
    const int gt   = tokBase + trow;
    const int eB   = g * 4;

    double acc64[4] = {0.0, 0.0, 0.0, 0.0};

    // staging map: round r -> q = r*256+tid; row q>>5 (32 float4/row), col q&31
    float4 pre[2];
#pragma unroll
    for (int r = 0; r < 2; ++r) {
        const int q = r * 256 + tid, t = q >> 5, c = (q & 31) << 2;
        pre[r] = *(const float4*)(x + (size_t)(tokBase + t) * DDIM + c);
    }
    int buf = 0;
#pragma unroll
    for (int r = 0; r < 2; ++r) {
        const int q = r * 256 + tid, t = q >> 5, c = (q & 31) << 2;
        *(float4*)&xs[buf * BUFSZ + t * STRIDE + c] = pre[r];
    }
    __syncthreads();

    for (int s = 0; s < NSTG; ++s) {
        const int kb = s * KS;
        if (s + 1 < NSTG) {  // prefetch next slice; in flight across compute
#pragma unroll
            for (int r = 0; r < 2; ++r) {
                const int q = r * 256 + tid, t = q >> 5, c = (q & 31) << 2;
                pre[r] = *(const float4*)(x + (size_t)(tokBase + t) * DDIM + kb + KS + c);
            }
        }
        const float* xr = &xs[buf * BUFSZ + trow * STRIDE];
#pragma unroll
        for (int kc = 0; kc < KS; kc += 32) {
            // fp32 within the 32-d chunk, fp64 across: top-2 indices must
            // match the np fp32 reference exactly (near-ties are the risk).
            float a0 = 0.f, a1 = 0.f, a2 = 0.f, a3 = 0.f;
#pragma unroll
            for (int dq = 0; dq < 8; ++dq) {
                const float4 xq = *(const float4*)(xr + kc + 4 * dq);
                const float xj[4] = {xq.x, xq.y, xq.z, xq.w};
#pragma unroll
                for (int j = 0; j < 4; ++j) {
                    const float4 w = *(const float4*)(W + (size_t)(kb + kc + 4 * dq + j) * NEXP + eB);
                    a0 = fmaf(xj[j], w.x, a0);
                    a1 = fmaf(xj[j], w.y, a1);
                    a2 = fmaf(xj[j], w.z, a2);
                    a3 = fmaf(xj[j], w.w, a3);
                }
            }
            acc64[0] += (double)a0; acc64[1] += (double)a1;
            acc64[2] += (double)a2; acc64[3] += (double)a3;
        }
        if (s + 1 < NSTG) {
            const int nb = buf ^ 1;
#pragma unroll
            for (int r = 0; r < 2; ++r) {
                const int q = r * 256 + tid, t = q >> 5, c = (q & 31) << 2;
                *(float4*)&xs[nb * BUFSZ + t * STRIDE + c] = pre[r];
            }
            __syncthreads();   // writers of nb done; readers of old buf done
            buf = nb;
        }
    }

    float* dispatch = out;
    float* probs    = out + (size_t)TTOT * NEXP;
    float* tkp      = out + (size_t)2 * TTOT * NEXP;
    float* tki      = tkp + (size_t)TTOT * 2;

    const float L[4] = {(float)acc64[0], (float)acc64[1],
                        (float)acc64[2], (float)acc64[3]};

    // softmax over 64 experts = 4 in-lane + 16-lane group (xor 1,2,4,8)
    float m = fmaxf(fmaxf(L[0], L[1]), fmaxf(L[2], L[3]));
#pragma unroll
    for (int off = 1; off < 16; off <<= 1) m = fmaxf(m, __shfl_xor(m, off, 64));
    float p[4];
    float s = 0.f;
#pragma unroll
    for (int i = 0; i < 4; ++i) { p[i] = expf(L[i] - m); s += p[i]; }
#pragma unroll
    for (int off = 1; off < 16; off <<= 1) s += __shfl_xor(s, off, 64);
    float pr[4];
#pragma unroll
    for (int i = 0; i < 4; ++i) pr[i] = p[i] / s;

    // in-lane top-2 (ascending idx: ties keep lower index, matching lax.top_k)
    float v1 = pr[0]; int i1 = eB; float v2 = -1.f; int i2 = -1;
#pragma unroll
    for (int k = 1; k < 4; ++k) {
        const float v = pr[k]; const int i = eB + k;
        if (v > v1) { v2 = v1; i2 = i1; v1 = v; i1 = i; }
        else if (v > v2) { v2 = v; i2 = i; }
    }
    // merge across the 16-lane token group
#pragma unroll
    for (int off = 1; off < 16; off <<= 1) {
        const float pv1 = __shfl_xor(v1, off, 64); const int pi1 = __shfl_xor(i1, off, 64);
        const float pv2 = __shfl_xor(v2, off, 64); const int pi2 = __shfl_xor(i2, off, 64);
        if (pv1 > v1 || (pv1 == v1 && pi1 < i1)) {
            float c2v = v1; int c2i = i1;
            if (pv2 > c2v || (pv2 == c2v && pi2 < c2i)) { c2v = pv2; c2i = pi2; }
            v1 = pv1; i1 = pi1; v2 = c2v; i2 = c2i;
        } else {
            if (pv1 > v2 || (pv1 == v2 && pi1 < i2)) { v2 = pv1; i2 = pi1; }
        }
    }

    *(float4*)&probs[(size_t)gt * NEXP + eB] = make_float4(pr[0], pr[1], pr[2], pr[3]);
    float4 dsp;
    dsp.x = (eB + 0 == i1 || eB + 0 == i2) ? 1.f : 0.f;
    dsp.y = (eB + 1 == i1 || eB + 1 == i2) ? 1.f : 0.f;
    dsp.z = (eB + 2 == i1 || eB + 2 == i2) ? 1.f : 0.f;
    dsp.w = (eB + 3 == i1 || eB + 3 == i2) ? 1.f : 0.f;
    *(float4*)&dispatch[(size_t)gt * NEXP + eB] = dsp;
    if (g == 0) {
        tkp[(size_t)gt * 2 + 0] = v1;
        tkp[(size_t)gt * 2 + 1] = v2;
        tki[(size_t)gt * 2 + 0] = (float)i1;
        tki[(size_t)gt * 2 + 1] = (float)i2;
    }
}

extern "C" void kernel_launch(void* const* d_in, const int* in_sizes, int n_in,
                              void* d_out, int out_size, void* d_ws, size_t ws_size,
                              hipStream_t stream) {
    const float* x = (const float*)d_in[0];
    const float* W = (const float*)d_in[1];
    float* out = (float*)d_out;
    moe_router<<<TTOT / TPB2, 256, 0, stream>>>(x, W, out);
}

// Round 6
// 492.233 us; speedup vs baseline: 9.2186x; 9.2186x over previous
//
#include <hip/hip_runtime.h>

#define TTOT 16384   // 4 * 4096 tokens
#define DDIM 2048
#define NEXP 64
#define TPB3 16      // tokens per block (4 waves: 2 token-octets x 2 expert-halves)
#define LSTR 68      // epilogue LDS row stride

// Wave = 8 tokens x 32 experts. lane: g = lane&7 -> experts [half*32+4g, +4),
// t = lane>>3 -> token. Both x and W are per-lane VMEM dwordx4 (vmcnt
// pipelining; no scalar-x lgkm serialization (R3), no uniform-addr VALU tax
// (R4), no LDS staging / deep prefetch -> no spills (R5)). W re-reads come
// from L2 (~524 MB total); x read <=2x (sibling half-wave, L2-hot).
__global__ __launch_bounds__(256, 4)
void moe_router(const float* __restrict__ x, const float* __restrict__ W,
                float* __restrict__ out)
{
    __shared__ float ls[TPB3][LSTR];
    const int tid  = threadIdx.x;
    const int lane = tid & 63;
    const int wq   = __builtin_amdgcn_readfirstlane(tid >> 6);  // 0..3
    const int half = wq & 1;        // expert half: [32h, 32h+32)
    const int tset = wq >> 1;       // token octet 0/1
    const int g    = lane & 7;      // expert quad within half
    const int t    = lane >> 3;     // token within octet
    const int tloc = tset * 8 + t;  // block-local token 0..15
    const int tokBase = blockIdx.x * TPB3;
    const int eB   = half * 32 + g * 4;

    const float* xp = x + (size_t)(tokBase + tloc) * DDIM;
    const float* wp = W + eB;

    double acc64[4] = {0.0, 0.0, 0.0, 0.0};

    // 64 chunks of 32 d. fp32 within a chunk, fp64 across chunks (top-2
    // indices must match the np fp32 reference exactly).
    for (int c = 0; c < 64; ++c) {
        const float* xc = xp + 32 * c;
        const float* wc = wp + (size_t)(32 * c) * NEXP;
        float a0 = 0.f, a1 = 0.f, a2 = 0.f, a3 = 0.f;
#pragma unroll
        for (int q = 0; q < 8; ++q) {
            const float4 xv = *(const float4*)(xc + 4 * q);
            const float xj[4] = {xv.x, xv.y, xv.z, xv.w};
#pragma unroll
            for (int j = 0; j < 4; ++j) {
                const float4 w = *(const float4*)(wc + (size_t)(4 * q + j) * NEXP);
                a0 = fmaf(xj[j], w.x, a0);
                a1 = fmaf(xj[j], w.y, a1);
                a2 = fmaf(xj[j], w.z, a2);
                a3 = fmaf(xj[j], w.w, a3);
            }
        }
        acc64[0] += (double)a0; acc64[1] += (double)a1;
        acc64[2] += (double)a2; acc64[3] += (double)a3;
    }

    // gather logits [16 tok][64 exp] into LDS (one-time)
    ls[tloc][eB + 0] = (float)acc64[0];
    ls[tloc][eB + 1] = (float)acc64[1];
    ls[tloc][eB + 2] = (float)acc64[2];
    ls[tloc][eB + 3] = (float)acc64[3];
    __syncthreads();

    float* dispatch = out;
    float* probs    = out + (size_t)TTOT * NEXP;
    float* tkp      = out + (size_t)2 * TTOT * NEXP;
    float* tki      = tkp + (size_t)TTOT * 2;

    // each wave: softmax + top-2 for 4 tokens, lane = expert (proven R3 code)
#pragma unroll
    for (int tt = 0; tt < 4; ++tt) {
        const int te = wq * 4 + tt;
        const int gt = tokBase + te;
        const float L = ls[te][lane];

        float m = L;
#pragma unroll
        for (int off = 32; off; off >>= 1) m = fmaxf(m, __shfl_xor(m, off, 64));
        const float p = expf(L - m);
        float s = p;
#pragma unroll
        for (int off = 32; off; off >>= 1) s += __shfl_xor(s, off, 64);
        const float prob = p / s;

        // top-1 (ties -> lowest index, matching lax.top_k / np)
        float v1 = prob; int i1 = lane;
#pragma unroll
        for (int off = 32; off; off >>= 1) {
            const float ov = __shfl_xor(v1, off, 64);
            const int   oi = __shfl_xor(i1, off, 64);
            if (ov > v1 || (ov == v1 && oi < i1)) { v1 = ov; i1 = oi; }
        }
        // top-2
        float v2 = (lane == i1) ? -1.0f : prob; int i2 = lane;
#pragma unroll
        for (int off = 32; off; off >>= 1) {
            const float ov = __shfl_xor(v2, off, 64);
            const int   oi = __shfl_xor(i2, off, 64);
            if (ov > v2 || (ov == v2 && oi < i2)) { v2 = ov; i2 = oi; }
        }

        probs[(size_t)gt * NEXP + lane]    = prob;
        dispatch[(size_t)gt * NEXP + lane] = (lane == i1 || lane == i2) ? 1.0f : 0.0f;
        if (lane == 0) {
            tkp[(size_t)gt * 2 + 0] = v1;
            tkp[(size_t)gt * 2 + 1] = v2;
            tki[(size_t)gt * 2 + 0] = (float)i1;
            tki[(size_t)gt * 2 + 1] = (float)i2;
        }
    }
}

extern "C" void kernel_launch(void* const* d_in, const int* in_sizes, int n_in,
                              void* d_out, int out_size, void* d_ws, size_t ws_size,
                              hipStream_t stream) {
    const float* x = (const float*)d_in[0];
    const float* W = (const float*)d_in[1];
    float* out = (float*)d_out;
    moe_router<<<TTOT / TPB3, 256, 0, stream>>>(x, W, out);
}

// Round 7
// 298.953 us; speedup vs baseline: 15.1786x; 1.6465x over previous
//
#include <hip/hip_runtime.h>

#define TTOT 16384        // 4 * 4096 tokens
#define DDIM 2048
#define NEXP 64
#define TPB  32           // tokens per block
#define SLICE 128         // d staged per slice
#define NSLICE (DDIM / SLICE)
#define XPAD 36           // LDS x-row: 32 tok + 4 pad (floats)
#define LPAD 67           // combine-buffer row (doubles)

// Block = 512 thr (8 waves) owns 32 tokens x 64 experts. Waves interleave
// 16-d chunks of a 128-d LDS slice (double-buffered). x staged TRANSPOSED
// [d][tok]: compute read = 2x ds_read_b128, 4 distinct bank-quads + 16-way
// same-address broadcast (free); staging writes 2-way (free). W: per-lane
// dwordx4 from L1 (T=8 token reuse -> 4.2 MB/CU = L1 floor; R6 showed L1
// doesn't dedup, so reuse must be in registers). Per lane: T=8 x E=4 block,
// fp32 chains per 16-d chunk + fp64 across chunks (proven numerics). 8-wave
// fp64 combine in LDS, then proven shuffle softmax/top-2.
__global__ __launch_bounds__(512, 4)
void moe_router(const float* __restrict__ x, const float* __restrict__ W,
                float* __restrict__ out)
{
    __shared__ float  xs[2][SLICE][XPAD];   // 36.9 KB
    __shared__ double L[TPB][LPAD];         // 17.2 KB
    const int tid  = threadIdx.x;
    const int lane = tid & 63;
    const int wq   = __builtin_amdgcn_readfirstlane(tid >> 6);  // 0..7
    const int eg   = lane & 15;       // experts [4eg, 4eg+4)
    const int tg   = lane >> 4;       // tokens  [8tg, 8tg+8)
    const int tokBase = blockIdx.x * TPB;

    // stager map: q = r*512 + tid -> token = q&31 (=tid&31), dq = q>>5
    const int st  = tid & 31;               // token row this thread stages
    const int sd0 = (tid >> 5) << 2;        // d-offset for r=0 (floats)
    const float* sx = x + (size_t)(tokBase + st) * DDIM;

    double acc64[8][4];
#pragma unroll
    for (int t = 0; t < 8; ++t)
#pragma unroll
        for (int j = 0; j < 4; ++j) acc64[t][j] = 0.0;

    // stage slice 0
    {
        float4 g0 = *(const float4*)(sx + sd0);
        float4 g1 = *(const float4*)(sx + 64 + sd0);
        const float v0[4] = {g0.x, g0.y, g0.z, g0.w};
        const float v1[4] = {g1.x, g1.y, g1.z, g1.w};
#pragma unroll
        for (int j = 0; j < 4; ++j) {
            xs[0][sd0 + j][st]      = v0[j];
            xs[0][64 + sd0 + j][st] = v1[j];
        }
    }
    __syncthreads();

    int buf = 0;
    for (int s = 0; s < NSLICE; ++s) {
        // issue next slice's global loads early (vmcnt in flight over compute)
        float4 g0, g1;
        if (s + 1 < NSLICE) {
            const float* nx = sx + (s + 1) * SLICE;
            g0 = *(const float4*)(nx + sd0);
            g1 = *(const float4*)(nx + 64 + sd0);
        }

        // compute this wave's 16-d chunk
        const int dbase = wq * 16;
        const float* Wp = W + (size_t)(s * SLICE + dbase) * NEXP + 4 * eg;
        float a32[8][4];
#pragma unroll
        for (int t = 0; t < 8; ++t)
#pragma unroll
            for (int j = 0; j < 4; ++j) a32[t][j] = 0.0f;

#pragma unroll 2
        for (int dd = 0; dd < 16; ++dd) {
            const float4 xa = *(const float4*)&xs[buf][dbase + dd][8 * tg];
            const float4 xb = *(const float4*)&xs[buf][dbase + dd][8 * tg + 4];
            const float4 w  = *(const float4*)(Wp + (size_t)dd * NEXP);
            const float xt[8] = {xa.x, xa.y, xa.z, xa.w, xb.x, xb.y, xb.z, xb.w};
            const float wj[4] = {w.x, w.y, w.z, w.w};
#pragma unroll
            for (int t = 0; t < 8; ++t)
#pragma unroll
                for (int j = 0; j < 4; ++j)
                    a32[t][j] = fmaf(xt[t], wj[j], a32[t][j]);
        }
#pragma unroll
        for (int t = 0; t < 8; ++t)
#pragma unroll
            for (int j = 0; j < 4; ++j) acc64[t][j] += (double)a32[t][j];

        // write next slice into the other buffer, one barrier per slice
        if (s + 1 < NSLICE) {
            const int nb = buf ^ 1;
            const float v0[4] = {g0.x, g0.y, g0.z, g0.w};
            const float v1[4] = {g1.x, g1.y, g1.z, g1.w};
#pragma unroll
            for (int j = 0; j < 4; ++j) {
                xs[nb][sd0 + j][st]      = v0[j];
                xs[nb][64 + sd0 + j][st] = v1[j];
            }
            __syncthreads();
            buf = nb;
        }
    }
    __syncthreads();

    // combine the 8 waves' fp64 partials in LDS (sequential, one-time)
    for (int w = 0; w < 8; ++w) {
        if (wq == w) {
#pragma unroll
            for (int t = 0; t < 8; ++t)
#pragma unroll
                for (int j = 0; j < 4; ++j) {
                    if (w == 0) L[8 * tg + t][4 * eg + j] = acc64[t][j];
                    else        L[8 * tg + t][4 * eg + j] += acc64[t][j];
                }
        }
        __syncthreads();
    }

    float* dispatch = out;
    float* probs    = out + (size_t)TTOT * NEXP;
    float* tkp      = out + (size_t)2 * TTOT * NEXP;
    float* tki      = tkp + (size_t)TTOT * 2;

    // each wave: softmax + top-2 for 4 tokens, lane = expert (proven code)
#pragma unroll
    for (int tt = 0; tt < 4; ++tt) {
        const int te = wq * 4 + tt;
        const int gt = tokBase + te;
        const float Lg = (float)L[te][lane];

        float m = Lg;
#pragma unroll
        for (int off = 32; off; off >>= 1) m = fmaxf(m, __shfl_xor(m, off, 64));
        const float p = expf(Lg - m);
        float sden = p;
#pragma unroll
        for (int off = 32; off; off >>= 1) sden += __shfl_xor(sden, off, 64);
        const float prob = p / sden;

        // top-1 (ties -> lowest index, matching lax.top_k / np)
        float v1 = prob; int i1 = lane;
#pragma unroll
        for (int off = 32; off; off >>= 1) {
            const float ov = __shfl_xor(v1, off, 64);
            const int   oi = __shfl_xor(i1, off, 64);
            if (ov > v1 || (ov == v1 && oi < i1)) { v1 = ov; i1 = oi; }
        }
        // top-2
        float v2 = (lane == i1) ? -1.0f : prob; int i2 = lane;
#pragma unroll
        for (int off = 32; off; off >>= 1) {
            const float ov = __shfl_xor(v2, off, 64);
            const int   oi = __shfl_xor(i2, off, 64);
            if (ov > v2 || (ov == v2 && oi < i2)) { v2 = ov; i2 = oi; }
        }

        probs[(size_t)gt * NEXP + lane]    = prob;
        dispatch[(size_t)gt * NEXP + lane] = (lane == i1 || lane == i2) ? 1.0f : 0.0f;
        if (lane == 0) {
            tkp[(size_t)gt * 2 + 0] = v1;
            tkp[(size_t)gt * 2 + 1] = v2;
            tki[(size_t)gt * 2 + 0] = (float)i1;
            tki[(size_t)gt * 2 + 1] = (float)i2;
        }
    }
}

extern "C" void kernel_launch(void* const* d_in, const int* in_sizes, int n_in,
                              void* d_out, int out_size, void* d_ws, size_t ws_size,
                              hipStream_t stream) {
    const float* x = (const float*)d_in[0];
    const float* W = (const float*)d_in[1];
    float* out = (float*)d_out;
    moe_router<<<TTOT / TPB, 512, 0, stream>>>(x, W, out);
}